// Round 2
// baseline (1343.444 us; speedup 1.0000x reference)
//
#include <hip/hip_runtime.h>

#define BATCH   4096
#define NRULES  512
#define NNEUR   128

typedef float f32x4 __attribute__((ext_vector_type(4)));

// Kernel 1: head_t[n][b] = dot(x[n][b][:], head_w[n][:]) + head_b[n]
//
// Layout: 8 lanes per row. lane = 8*q + i; wave handles 8 rows (q) per
// chunk, 8 chunks (64 consecutive b, same n) per wave.
// Per k-iteration each row-octet (8 lanes) reads 128 B contiguous
// (2 full 64B lines) -> fully coalesced; 16 float4 loads per lane per
// chunk = deep MLP. head_w fragment (16 x float4, depends only on i)
// is register-resident and reused across all 64 b handled by the wave.
// Cross-lane reduce: 3 shfl_xor (1,2,4) within the 8-lane group reduces
// ALL 8 rows at once (vs 48 shuffles for per-row 64-lane butterflies).
__global__ __launch_bounds__(256) void head_kernel(
    const float* __restrict__ x,
    const float* __restrict__ head_w,
    const float* __restrict__ head_b,
    float* __restrict__ head_t)   // [NNEUR][BATCH]
{
    const int lane = threadIdx.x & 63;
    const int wv   = threadIdx.x >> 6;
    const int i    = lane & 7;    // position within row
    const int q    = lane >> 3;   // row within chunk

    const int wg    = blockIdx.x * 4 + wv;   // 0..8191
    const int n     = wg >> 6;               // 64 waves per neuron
    const int bbase = (wg & 63) << 6;        // 64 b-values per wave

    // head_w fragment: w[k] covers rules [4i+32k, 4i+32k+4). L2-resident,
    // loaded once per wave, reused for 64 rows.
    const f32x4* wp = (const f32x4*)(head_w + (size_t)n * NRULES);
    f32x4 w[16];
#pragma unroll
    for (int k = 0; k < 16; ++k) w[k] = wp[i + 8 * k];

    const float hb = head_b[n];
    float* hrow = head_t + (size_t)n * BATCH;

#pragma unroll 1
    for (int c = 0; c < 8; ++c) {
        const int b0 = bbase + c * 8;
        const f32x4* xp =
            (const f32x4*)(x + ((size_t)n * BATCH + b0 + q) * NRULES);
        f32x4 acc = {0.0f, 0.0f, 0.0f, 0.0f};
#pragma unroll
        for (int k = 0; k < 16; ++k) {
            f32x4 v = xp[i + 8 * k];
            acc += v * w[k];
        }
        float s = (acc[0] + acc[1]) + (acc[2] + acc[3]);
        // reduce across the 8 lanes of this row-octet (3 steps)
        s += __shfl_xor(s, 1, 64);
        s += __shfl_xor(s, 2, 64);
        s += __shfl_xor(s, 4, 64);
        if (i == 0) hrow[b0 + q] = s + hb;   // 8 lanes -> 32 B contiguous
    }
}

// Kernel 2: logits + softmax. 32 blocks x 512 threads.
// Block handles 128 consecutive b. thread t: bl = t&127, quarter = t>>7;
// accumulates n in [32*quarter, 32*quarter+32) -> coalesced 256 B reads
// of head_t per instruction. LDS combine across quarters, softmax of 2,
// coalesced float2 store.
__global__ __launch_bounds__(512) void foot_kernel(
    const float* __restrict__ head_t,  // [NNEUR][BATCH]
    const float* __restrict__ foot_w,  // [2][NNEUR]
    const float* __restrict__ foot_b,  // [2]
    float* __restrict__ out)           // [BATCH][2]
{
    __shared__ float p0[4][128];
    __shared__ float p1[4][128];

    const int t  = threadIdx.x;
    const int bl = t & 127;
    const int qt = t >> 7;           // 0..3
    const int b0 = blockIdx.x * 128;

    float l0 = 0.0f, l1 = 0.0f;
    const int n0 = qt * 32;
#pragma unroll 8
    for (int k = 0; k < 32; ++k) {
        const int n = n0 + k;
        const float h = head_t[(size_t)n * BATCH + b0 + bl];
        l0 = fmaf(h, foot_w[n], l0);
        l1 = fmaf(h, foot_w[NNEUR + n], l1);
    }
    p0[qt][bl] = l0;
    p1[qt][bl] = l1;
    __syncthreads();

    if (t < 128) {
        float a0 = (p0[0][bl] + p0[1][bl]) + (p0[2][bl] + p0[3][bl]);
        float a1 = (p1[0][bl] + p1[1][bl]) + (p1[2][bl] + p1[3][bl]);
        a0 += foot_b[0];
        a1 += foot_b[1];
        const float m  = fmaxf(a0, a1);
        const float e0 = __expf(a0 - m);
        const float e1 = __expf(a1 - m);
        const float inv = 1.0f / (e0 + e1);
        float2 r;
        r.x = e0 * inv;
        r.y = e1 * inv;
        *(float2*)(out + 2 * (b0 + bl)) = r;
    }
}

extern "C" void kernel_launch(void* const* d_in, const int* in_sizes, int n_in,
                              void* d_out, int out_size, void* d_ws, size_t ws_size,
                              hipStream_t stream) {
    const float* x      = (const float*)d_in[0];
    const float* head_w = (const float*)d_in[1];
    const float* head_b = (const float*)d_in[2];
    const float* foot_w = (const float*)d_in[3];
    const float* foot_b = (const float*)d_in[4];
    float* out    = (float*)d_out;
    float* head_t = (float*)d_ws;   // NNEUR*BATCH*4 = 2 MiB scratch, [N][B]

    // kernel 1: 8192 waves (64 per neuron), 4 waves/block -> 2048 blocks
    head_kernel<<<2048, 256, 0, stream>>>(x, head_w, head_b, head_t);

    // kernel 2: 32 blocks x 512 threads
    foot_kernel<<<32, 512, 0, stream>>>(head_t, foot_w, foot_b, out);
}